// Round 3
// baseline (26.658 us; speedup 1.0000x reference)
//
#include <hip/hip_runtime.h>

// pose3d_calibration: B=262144 poses, J=15.
// out[0] = mean_{B,6} (|bone_l|^2 - |bone_r|^2)^2
// out[1] = mean_{B,2,15} (project(R^T (X - C)) - pose2d)^2
//
// Memory-bound streaming reduction: 348 B/pose in, 8 B out.
// R3: coalesced global->LDS staging (widths 16/4 only), single-wave blocks
// with EXPLICIT s_waitcnt vmcnt(0) (single-wave __syncthreads does not drain
// vmcnt -> R2's garbage), full-f64 per-pose math (R1 bit-matched ref).

typedef const __attribute__((address_space(1))) void* gas1_t;
typedef __attribute__((address_space(3))) void* las3_t;

__device__ __forceinline__ void gl16(const float* g, float* l) {
    __builtin_amdgcn_global_load_lds((gas1_t)g, (las3_t)l, 16, 0, 0);
}
__device__ __forceinline__ void gl4(const float* g, float* l) {
    __builtin_amdgcn_global_load_lds((gas1_t)g, (las3_t)l, 4, 0, 0);
}

#define SLABS 4   // 64-pose slabs per block

// One wave (64 lanes) per block; 4 sequential slabs of 64 consecutive poses.
// LDS: pose3d 2880f + pose2d 1920f + R 576f + C 192f = 22272 B.
__global__ __launch_bounds__(64) void pose_calib_main(
    const float* __restrict__ pose3d,   // (B,3,15)
    const float* __restrict__ pose2d,   // (B,2,15)
    const float* __restrict__ Rd,       // (B,3,3)
    const float* __restrict__ Cd,       // (B,3,1)
    double* __restrict__ partial,       // (gridDim.x, 2)
    int B)
{
    __shared__ float sX[2880];
    __shared__ float sP2[1920];
    __shared__ float sR[576];
    __shared__ float sC[192];

    const int lane = threadIdx.x;   // 0..63
    double sym_d = 0.0, proj_d = 0.0;

    const long long slab0 = (long long)blockIdx.x * SLABS;

    for (int s = 0; s < SLABS; ++s) {
        const long long p0 = (slab0 + s) * 64;
        if (p0 >= (long long)B) break;
        const bool full = (p0 + 64 <= (long long)B);

        float X[45], pu[15], pv[15], Rr[9], Cc[3];
        bool active;

        if (full) {
            if (s > 0)  // previous slab's ds_reads must retire before overwrite
                asm volatile("s_waitcnt lgkmcnt(0)" ::: "memory");

            const float* g3 = pose3d + p0 * 45;
            const float* g2 = pose2d + p0 * 30;
            const float* gR = Rd + p0 * 9;
            const float* gC = Cd + p0 * 3;

            // pose3d: 11 x 1024B + 1 x 256B
            #pragma unroll
            for (int k = 0; k < 11; ++k) gl16(g3 + k * 256 + lane * 4, sX + k * 256);
            gl4(g3 + 2816 + lane, sX + 2816);
            // pose2d: 7 x 1024B + 2 x 256B
            #pragma unroll
            for (int k = 0; k < 7; ++k) gl16(g2 + k * 256 + lane * 4, sP2 + k * 256);
            gl4(g2 + 1792 + lane, sP2 + 1792);
            gl4(g2 + 1856 + lane, sP2 + 1856);
            // R: 2 x 1024B + 1 x 256B
            gl16(gR + lane * 4, sR);
            gl16(gR + 256 + lane * 4, sR + 256);
            gl4(gR + 512 + lane, sR + 512);
            // C: 3 x 256B
            gl4(gC + lane, sC);
            gl4(gC + 64 + lane, sC + 64);
            gl4(gC + 128 + lane, sC + 128);

            // global_load_lds completion is vmcnt-tracked; wait explicitly
            asm volatile("s_waitcnt vmcnt(0)" ::: "memory");

            active = true;
            #pragma unroll
            for (int i = 0; i < 45; ++i) X[i] = sX[lane * 45 + i];      // stride 45 (odd): 2/bank, free
            #pragma unroll
            for (int j = 0; j < 15; ++j) { pu[j] = sP2[lane * 30 + j]; pv[j] = sP2[lane * 30 + 15 + j]; }
            #pragma unroll
            for (int k = 0; k < 9; ++k) Rr[k] = sR[lane * 9 + k];
            #pragma unroll
            for (int c = 0; c < 3; ++c) Cc[c] = sC[lane * 3 + c];
        } else {
            // tail slab (not hit at B=262144): guarded scalar loads
            const long long p = p0 + lane;
            active = (p < (long long)B);
            if (active) {
                const float* g3 = pose3d + p * 45;
                const float* g2 = pose2d + p * 30;
                const float* gR = Rd + p * 9;
                const float* gC = Cd + p * 3;
                #pragma unroll
                for (int i = 0; i < 45; ++i) X[i] = g3[i];
                #pragma unroll
                for (int j = 0; j < 15; ++j) { pu[j] = g2[j]; pv[j] = g2[15 + j]; }
                #pragma unroll
                for (int k = 0; k < 9; ++k) Rr[k] = gR[k];
                #pragma unroll
                for (int c = 0; c < 3; ++c) Cc[c] = gC[c];
            }
        }

        if (active) {
            const int lb0[6] = {1, 5, 6, 14, 11, 12}, lb1[6] = {5, 6, 7, 11, 12, 13};
            const int rb0[6] = {1, 2, 3, 14, 8, 9},   rb1[6] = {2, 3, 4, 8, 9, 10};
            #pragma unroll
            for (int k = 0; k < 6; ++k) {
                double ll = 0.0, lr = 0.0;
                #pragma unroll
                for (int c = 0; c < 3; ++c) {
                    double dl = (double)X[c * 15 + lb0[k]] - (double)X[c * 15 + lb1[k]];
                    double dr = (double)X[c * 15 + rb0[k]] - (double)X[c * 15 + rb1[k]];
                    ll += dl * dl;
                    lr += dr * dr;
                }
                double d = ll - lr;
                sym_d += d * d;
            }

            const double R00 = Rr[0], R01 = Rr[1], R02 = Rr[2];
            const double R10 = Rr[3], R11 = Rr[4], R12 = Rr[5];
            const double R20 = Rr[6], R21 = Rr[7], R22 = Rr[8];
            const double C0 = Cc[0], C1 = Cc[1], C2 = Cc[2];
            #pragma unroll
            for (int j = 0; j < 15; ++j) {
                double q0 = (double)X[j]      - C0;
                double q1 = (double)X[15 + j] - C1;
                double q2 = (double)X[30 + j] - C2;
                double P0 = R00 * q0 + R10 * q1 + R20 * q2;
                double P1 = R01 * q0 + R11 * q1 + R21 * q2;
                double P2 = R02 * q0 + R12 * q1 + R22 * q2;
                double rz = 1.0 / P2;
                double du = 512.0 * P0 * rz + 512.0 - (double)pu[j];
                double dv = 512.0 * P1 * rz + 256.0 - (double)pv[j];
                proj_d += du * du + dv * dv;
            }
        }
    }

    // wave-wide f64 reduction (single wave per block)
    #pragma unroll
    for (int off = 32; off > 0; off >>= 1) {
        sym_d  += __shfl_down(sym_d,  off, 64);
        proj_d += __shfl_down(proj_d, off, 64);
    }
    if (lane == 0) {
        partial[2 * (size_t)blockIdx.x]     = sym_d;
        partial[2 * (size_t)blockIdx.x + 1] = proj_d;
    }
}

__global__ __launch_bounds__(256) void pose_calib_finish(
    const double* __restrict__ partial, int nblk,
    float* __restrict__ out, double inv_n_sym, double inv_n_proj)
{
    const double2* p2 = (const double2*)partial;
    double ss = 0.0, pp = 0.0;
    for (int i = threadIdx.x; i < nblk; i += 256) {
        double2 v = p2[i];
        ss += v.x;
        pp += v.y;
    }
    #pragma unroll
    for (int off = 32; off > 0; off >>= 1) {
        ss += __shfl_down(ss, off, 64);
        pp += __shfl_down(pp, off, 64);
    }
    __shared__ double s_s[4], s_p[4];
    const int lane = threadIdx.x & 63;
    const int wid  = threadIdx.x >> 6;
    if (lane == 0) { s_s[wid] = ss; s_p[wid] = pp; }
    __syncthreads();
    if (threadIdx.x == 0) {
        double S = s_s[0] + s_s[1] + s_s[2] + s_s[3];
        double P = s_p[0] + s_p[1] + s_p[2] + s_p[3];
        out[0] = (float)(S * inv_n_sym);
        out[1] = (float)(P * inv_n_proj);
    }
}

extern "C" void kernel_launch(void* const* d_in, const int* in_sizes, int n_in,
                              void* d_out, int out_size, void* d_ws, size_t ws_size,
                              hipStream_t stream) {
    const float* pose3d = (const float*)d_in[0];
    const float* pose2d = (const float*)d_in[1];
    const float* Rd     = (const float*)d_in[2];
    const float* Cd     = (const float*)d_in[3];

    const int B = in_sizes[3] / 3;                 // C_drone is (B,3,1)
    const int nslab = (B + 63) / 64;
    const int nblk  = (nslab + SLABS - 1) / SLABS; // 1024 @ B=262144

    double* partial = (double*)d_ws;               // nblk*2 doubles (16 KB)

    pose_calib_main<<<nblk, 64, 0, stream>>>(pose3d, pose2d, Rd, Cd, partial, B);
    pose_calib_finish<<<1, 256, 0, stream>>>(
        partial, nblk, (float*)d_out,
        1.0 / ((double)B * 6.0), 1.0 / ((double)B * 30.0));
}

// Round 4
// 22.455 us; speedup vs baseline: 1.1872x; 1.1872x over previous
//
#include <hip/hip_runtime.h>

// pose3d_calibration: B=262144 poses, J=15.
// out[0] = mean_{B,6} (|bone_l|^2 - |bone_r|^2)^2
// out[1] = mean_{B,2,15} (project(R^T (X - C)) - pose2d)^2
//
// R4: per-thread VECTORIZED register loads (float4 @ 4B alignment), no LDS,
// no barriers. R3's LDS staging was correct but latency-serialized (1 wave/
// SIMD + vmcnt(0) per slab). Here: 25 wide VMEM instrs/pose (vs 87 scalar),
// 25-deep MLP per thread, ~3 waves/SIMD. f64 math (bit-matches np ref).

typedef float f4u __attribute__((ext_vector_type(4), aligned(4)));
typedef float f2u __attribute__((ext_vector_type(2), aligned(4)));

__global__ __launch_bounds__(256) void pose_calib_main(
    const float* __restrict__ pose3d,   // (B,3,15)
    const float* __restrict__ pose2d,   // (B,2,15)
    const float* __restrict__ Rd,       // (B,3,3)
    const float* __restrict__ Cd,       // (B,3,1)
    double* __restrict__ partial,       // (gridDim.x, 2)
    int B)
{
    const int p = blockIdx.x * 256 + threadIdx.x;
    double sym_d = 0.0, proj_d = 0.0;

    if (p < B) {
        const float* g3 = pose3d + (size_t)p * 45;
        const float* g2 = pose2d + (size_t)p * 30;
        const float* gR = Rd + (size_t)p * 9;
        const float* gC = Cd + (size_t)p * 3;

        // ---- issue all loads first (wide, 4B-aligned) ----
        float X[45], pu[15], pv[15], Rr[9], Cc[3];
        #pragma unroll
        for (int k = 0; k < 11; ++k) {
            f4u v = *(const f4u*)(g3 + 4 * k);
            X[4 * k] = v.x; X[4 * k + 1] = v.y; X[4 * k + 2] = v.z; X[4 * k + 3] = v.w;
        }
        X[44] = g3[44];
        #pragma unroll
        for (int k = 0; k < 7; ++k) {
            f4u v = *(const f4u*)(g2 + 4 * k);
            float* d = (k < 4) ? &pu[4 * k] : &pv[4 * k - 15];
            // avoid dynamic pointer games; just index directly:
            (void)d;
            int base = 4 * k;
            float vals[4] = {v.x, v.y, v.z, v.w};
            #pragma unroll
            for (int t = 0; t < 4; ++t) {
                int idx = base + t;
                if (idx < 15) pu[idx] = vals[t]; else pv[idx - 15] = vals[t];
            }
        }
        { f2u v = *(const f2u*)(g2 + 28); pv[13] = v.x; pv[14] = v.y; }
        { f4u v = *(const f4u*)(gR); Rr[0] = v.x; Rr[1] = v.y; Rr[2] = v.z; Rr[3] = v.w; }
        { f4u v = *(const f4u*)(gR + 4); Rr[4] = v.x; Rr[5] = v.y; Rr[6] = v.z; Rr[7] = v.w; }
        Rr[8] = gR[8];
        { f2u v = *(const f2u*)(gC); Cc[0] = v.x; Cc[1] = v.y; }
        Cc[2] = gC[2];

        // ---- bone symmetry (f64) ----
        const int lb0[6] = {1, 5, 6, 14, 11, 12}, lb1[6] = {5, 6, 7, 11, 12, 13};
        const int rb0[6] = {1, 2, 3, 14, 8, 9},   rb1[6] = {2, 3, 4, 8, 9, 10};
        #pragma unroll
        for (int k = 0; k < 6; ++k) {
            double ll = 0.0, lr = 0.0;
            #pragma unroll
            for (int c = 0; c < 3; ++c) {
                double dl = (double)X[c * 15 + lb0[k]] - (double)X[c * 15 + lb1[k]];
                double dr = (double)X[c * 15 + rb0[k]] - (double)X[c * 15 + rb1[k]];
                ll += dl * dl;
                lr += dr * dr;
            }
            double d = ll - lr;
            sym_d += d * d;
        }

        // ---- projection (f64): P = R^T (X - C), u = 512 x/z + 512, v = 512 y/z + 256 ----
        const double R00 = Rr[0], R01 = Rr[1], R02 = Rr[2];
        const double R10 = Rr[3], R11 = Rr[4], R12 = Rr[5];
        const double R20 = Rr[6], R21 = Rr[7], R22 = Rr[8];
        const double C0 = Cc[0], C1 = Cc[1], C2 = Cc[2];
        #pragma unroll
        for (int j = 0; j < 15; ++j) {
            double q0 = (double)X[j]      - C0;
            double q1 = (double)X[15 + j] - C1;
            double q2 = (double)X[30 + j] - C2;
            double P0 = R00 * q0 + R10 * q1 + R20 * q2;
            double P1 = R01 * q0 + R11 * q1 + R21 * q2;
            double P2 = R02 * q0 + R12 * q1 + R22 * q2;
            double rz = 1.0 / P2;
            double du = 512.0 * P0 * rz + 512.0 - (double)pu[j];
            double dv = 512.0 * P1 * rz + 256.0 - (double)pv[j];
            proj_d += du * du + dv * dv;
        }
    }

    // wave shfl reduce -> LDS across 4 waves -> per-block partial
    #pragma unroll
    for (int off = 32; off > 0; off >>= 1) {
        sym_d  += __shfl_down(sym_d,  off, 64);
        proj_d += __shfl_down(proj_d, off, 64);
    }
    __shared__ double s_sym[4], s_proj[4];
    const int lane = threadIdx.x & 63;
    const int wid  = threadIdx.x >> 6;
    if (lane == 0) { s_sym[wid] = sym_d; s_proj[wid] = proj_d; }
    __syncthreads();
    if (threadIdx.x == 0) {
        partial[2 * (size_t)blockIdx.x]     = s_sym[0] + s_sym[1] + s_sym[2] + s_sym[3];
        partial[2 * (size_t)blockIdx.x + 1] = s_proj[0] + s_proj[1] + s_proj[2] + s_proj[3];
    }
}

__global__ __launch_bounds__(256) void pose_calib_finish(
    const double* __restrict__ partial, int nblk,
    float* __restrict__ out, double inv_n_sym, double inv_n_proj)
{
    const double2* p2 = (const double2*)partial;
    double ss = 0.0, pp = 0.0;
    for (int i = threadIdx.x; i < nblk; i += 256) {
        double2 v = p2[i];
        ss += v.x;
        pp += v.y;
    }
    #pragma unroll
    for (int off = 32; off > 0; off >>= 1) {
        ss += __shfl_down(ss, off, 64);
        pp += __shfl_down(pp, off, 64);
    }
    __shared__ double s_s[4], s_p[4];
    const int lane = threadIdx.x & 63;
    const int wid  = threadIdx.x >> 6;
    if (lane == 0) { s_s[wid] = ss; s_p[wid] = pp; }
    __syncthreads();
    if (threadIdx.x == 0) {
        double S = s_s[0] + s_s[1] + s_s[2] + s_s[3];
        double P = s_p[0] + s_p[1] + s_p[2] + s_p[3];
        out[0] = (float)(S * inv_n_sym);
        out[1] = (float)(P * inv_n_proj);
    }
}

extern "C" void kernel_launch(void* const* d_in, const int* in_sizes, int n_in,
                              void* d_out, int out_size, void* d_ws, size_t ws_size,
                              hipStream_t stream) {
    const float* pose3d = (const float*)d_in[0];
    const float* pose2d = (const float*)d_in[1];
    const float* Rd     = (const float*)d_in[2];
    const float* Cd     = (const float*)d_in[3];

    const int B = in_sizes[3] / 3;                 // C_drone is (B,3,1)
    const int nblk = (B + 255) / 256;              // 1024 @ B=262144

    double* partial = (double*)d_ws;               // nblk*2 doubles (16 KB)

    pose_calib_main<<<nblk, 256, 0, stream>>>(pose3d, pose2d, Rd, Cd, partial, B);
    pose_calib_finish<<<1, 256, 0, stream>>>(
        partial, nblk, (float*)d_out,
        1.0 / ((double)B * 6.0), 1.0 / ((double)B * 30.0));
}